// Round 20
// baseline (113.119 us; speedup 1.0000x reference)
//
#include <hip/hip_runtime.h>
#include <hip/hip_bf16.h>

// Problem constants
constexpr int B = 8, N = 4096, D = 768;
constexpr int H = 12, K = 16, U = 4, V = 64, L = 23, PAD = 11;
constexpr int CQ = 192;           // q channels [0,192)
constexpr int CK = 64;            // k channels [192,256)
constexpr int CV = 256;           // v channels [256,512)
constexpr int CT = 512;           // total channels
constexpr int CV0 = CQ + CK;      // 256
constexpr float EPS = 1e-5f;

typedef _Float16 f16x8 __attribute__((ext_vector_type(8)));
typedef _Float16 f16x4 __attribute__((ext_vector_type(4)));
typedef _Float16 f16x2 __attribute__((ext_vector_type(2)));
typedef float    f32x4 __attribute__((ext_vector_type(4)));

#define GLOAD16(gp, lp) __builtin_amdgcn_global_load_lds( \
    (const __attribute__((address_space(1))) void*)(gp),  \
    (__attribute__((address_space(3))) void*)(lp), 16, 0, 0)

__device__ __forceinline__ f16x2 pkrtz(float a, float b) {
    return __builtin_bit_cast(f16x2, __builtin_amdgcn_cvt_pkrtz(a, b));
}

__device__ __forceinline__ f16x8 cvt8r(float4 a, float4 b) {
    f16x8 r;
    r[0] = (_Float16)a.x; r[1] = (_Float16)a.y; r[2] = (_Float16)a.z; r[3] = (_Float16)a.w;
    r[4] = (_Float16)b.x; r[5] = (_Float16)b.y; r[6] = (_Float16)b.z; r[7] = (_Float16)b.w;
    return r;
}

// ---------------------------------------------------------------------------
// K0: bid<192: pack Wq|Wk|Wv -> Wh[512][768] f16.
//     bid>=192 (8 blocks): precompute shifted rel table to GLOBAL relSg.
// ---------------------------------------------------------------------------
__global__ __launch_bounds__(256) void k_w16(
    const float* __restrict__ Wq, const float* __restrict__ Wk,
    const float* __restrict__ Wv, const float* __restrict__ rel,
    _Float16* __restrict__ Wh, _Float16* __restrict__ relSg)
{
    const int bid = blockIdx.x;
    const int tid = threadIdx.x;
    if (bid < 192) {
        const int idx = bid * 256 + tid;   // 49152 groups of 8
        const int c = idx / 96, g = idx % 96;
        const float* src;
        if (c < CQ)       src = Wq + (size_t)c * D;
        else if (c < CV0) src = Wk + (size_t)(c - CQ) * D;
        else              src = Wv + (size_t)(c - CV0) * D;
        float4 a = *(const float4*)(src + g * 8);
        float4 b = *(const float4*)(src + g * 8 + 4);
        *(f16x8*)(Wh + (size_t)c * D + g * 8) = cvt8r(a, b);
    } else {
        const int base = ((bid - 192) * 256 + tid) * 8;
        f16x8 o;
        #pragma unroll
        for (int j = 0; j < 8; ++j) {
            const int e = base + j;
            const int jj = e & 31, kk = (e >> 5) & 15;
            const int uu = (e >> 9) & 3, dd = e >> 11;
            const int l = jj - dd;
            float v = (l >= 0 && l < L) ? rel[(kk * U + uu) * L + l] : 0.f;
            o[j] = (_Float16)v;
        }
        *(f16x8*)(relSg + base) = o;
    }
}

// ---------------------------------------------------------------------------
// K1: projection GEMM — 512c x 128n tile, 8 waves, ring-3 A + ring-3 B(f16).
//   B now stored f16 in LDS (reads 4 b128/wave vs 8 for f32) via reg-staging
//   with contiguous 128B-per-row source; cvt in staging, not compute path.
//   Count-robust schedule (no vmcnt arithmetic): phase t =
//     { vmcnt(0) [drains t-1's 6 loads, 1 full phase in flight];
//       ds_write Bs(t+1) from carried regs; ds_read af/bf(t);
//       load B(t+2) regs + gload A(t+2); lgkm0; BAR; MFMA(t); BAR }.
//   LDS: A 3x32 KB + B 3x8 KB = 120 KB -> 1 block/CU (no VGPR cap, no spill).
// ---------------------------------------------------------------------------
__global__ __launch_bounds__(512) void k_proj(
    const float* __restrict__ x, const _Float16* __restrict__ Wh,
    _Float16* __restrict__ Ph)
{
    __shared__ _Float16 As0[512 * 32], As1[512 * 32], As2[512 * 32];
    __shared__ _Float16 Bs0[128 * 32], Bs1[128 * 32], Bs2[128 * 32];
    const int b  = blockIdx.z;
    const int bn = blockIdx.x * 128;
    const int tid  = threadIdx.x;
    const int lane = tid & 63;
    const int wave = tid >> 6;        // 0..7
    const int wr  = wave >> 1;        // c quarter 0..3 (128c each)
    const int wcn = wave & 1;         // n half 0..1 (64n each)
    const int fr = lane & 15, sl = lane >> 4;

    // A staging: per wave 4 insts x (16 rows x 4 chunks of 16B)
    const int arow_l = lane >> 2;     // 0..15
    const int achk   = (lane & 3) ^ (arow_l & 3) ^ ((arow_l >> 2) & 3);

    // B staging (reg): thread = (row tb 0..127, logical 16B-chunk jq 0..3);
    // source 4 lanes x 32B = 128B contiguous per row; write to phys chunk
    // pq = jq ^ key(tb) — the same involution the frag read uses.
    const int tb = tid >> 2;
    const int jq = tid & 3;
    const int pq = jq ^ (tb & 3) ^ ((tb >> 2) & 3);
    const int boff = tb * 32 + pq * 8;                 // f16 elems
    const float* xsrc = x + ((size_t)b * N + bn + tb) * D + jq * 8;

    const _Float16* Wbase = Wh;                        // full 512 channels
    const int ca = sl ^ (fr & 3) ^ ((fr >> 2) & 3);    // frag chunk (A & B)

    f32x4 acc[8][4] = {};
    float4 xq0a{}, xq0b{}, xq1a{}, xq1b{};             // B reg slots 0/1

#define STAGE_A(Ap, kt) do {                                           \
        _Pragma("unroll")                                              \
        for (int j = 0; j < 4; ++j) {                                  \
            const int r0 = wave * 64 + j * 16;                         \
            GLOAD16(Wbase + (size_t)(r0 + arow_l) * D + (kt) + achk * 8, \
                    (Ap) + r0 * 32);                                   \
        }                                                              \
    } while (0)

#define WAIT0  asm volatile("s_waitcnt vmcnt(0)" ::: "memory")
#define LGKM0  asm volatile("s_waitcnt lgkmcnt(0)" ::: "memory")
#define BAR    __builtin_amdgcn_s_barrier()
#define SCHED0 __builtin_amdgcn_sched_barrier(0)

// Phase t: Acur/Bcur = bufs t%3; Anxt = As[(t+2)%3]; Bwr = Bs[(t+1)%3];
// XLa/XLb = load slot (t&1); XWa/XWb = write slot ((t+1)&1).
#define PH(Acur, Bcur, Anxt, Bwr, XLa, XLb, XWa, XWb, ktn, STG, WR, LAST) do { \
        WAIT0;                                                          \
        if (WR) *(f16x8*)((Bwr) + boff) = cvt8r(XWa, XWb);              \
        f16x8 af[8], bf[4];                                             \
        _Pragma("unroll")                                               \
        for (int ni = 0; ni < 4; ++ni)                                  \
            bf[ni] = *(const f16x8*)((Bcur) + (wcn * 64 + ni * 16 + fr) * 32 + ca * 8); \
        _Pragma("unroll")                                               \
        for (int mi = 0; mi < 8; ++mi)                                  \
            af[mi] = *(const f16x8*)((Acur) + (wr * 128 + mi * 16 + fr) * 32 + ca * 8); \
        if (STG) {                                                      \
            XLa = *(const float4*)(xsrc + (ktn));                       \
            XLb = *(const float4*)(xsrc + (ktn) + 4);                   \
            STAGE_A(Anxt, ktn);                                         \
        }                                                               \
        LGKM0; SCHED0; BAR;                                             \
        __builtin_amdgcn_s_setprio(1);                                  \
        _Pragma("unroll")                                               \
        for (int mi = 0; mi < 8; ++mi)                                  \
            _Pragma("unroll")                                           \
            for (int ni = 0; ni < 4; ++ni)                              \
                acc[mi][ni] = __builtin_amdgcn_mfma_f32_16x16x32_f16(   \
                    af[mi], bf[ni], acc[mi][ni], 0, 0, 0);              \
        __builtin_amdgcn_s_setprio(0);                                  \
        if (!LAST) { SCHED0; BAR; }                                     \
    } while (0)

    // prologue: tiles 0 and 1 fully staged (A via gload, B via regs)
    xq0a = *(const float4*)(xsrc);
    xq0b = *(const float4*)(xsrc + 4);
    xq1a = *(const float4*)(xsrc + 32);
    xq1b = *(const float4*)(xsrc + 36);
    STAGE_A(As0, 0);
    STAGE_A(As1, 32);
    WAIT0;
    *(f16x8*)(Bs0 + boff) = cvt8r(xq0a, xq0b);
    *(f16x8*)(Bs1 + boff) = cvt8r(xq1a, xq1b);
    LGKM0; SCHED0; BAR;

    // 24 phases; tiles staged 2..23 by phases 0..21.
    PH(As0, Bs0, As2, Bs1, xq0a, xq0b, xq1a, xq1b,  64, 1, 0, 0);  // t=0
    PH(As1, Bs1, As0, Bs2, xq1a, xq1b, xq0a, xq0b,  96, 1, 1, 0);  // t=1
    PH(As2, Bs2, As1, Bs0, xq0a, xq0b, xq1a, xq1b, 128, 1, 1, 0);  // t=2
    PH(As0, Bs0, As2, Bs1, xq1a, xq1b, xq0a, xq0b, 160, 1, 1, 0);  // t=3
    PH(As1, Bs1, As0, Bs2, xq0a, xq0b, xq1a, xq1b, 192, 1, 1, 0);  // t=4
    PH(As2, Bs2, As1, Bs0, xq1a, xq1b, xq0a, xq0b, 224, 1, 1, 0);  // t=5
    PH(As0, Bs0, As2, Bs1, xq0a, xq0b, xq1a, xq1b, 256, 1, 1, 0);  // t=6
    PH(As1, Bs1, As0, Bs2, xq1a, xq1b, xq0a, xq0b, 288, 1, 1, 0);  // t=7
    PH(As2, Bs2, As1, Bs0, xq0a, xq0b, xq1a, xq1b, 320, 1, 1, 0);  // t=8
    PH(As0, Bs0, As2, Bs1, xq1a, xq1b, xq0a, xq0b, 352, 1, 1, 0);  // t=9
    PH(As1, Bs1, As0, Bs2, xq0a, xq0b, xq1a, xq1b, 384, 1, 1, 0);  // t=10
    PH(As2, Bs2, As1, Bs0, xq1a, xq1b, xq0a, xq0b, 416, 1, 1, 0);  // t=11
    PH(As0, Bs0, As2, Bs1, xq0a, xq0b, xq1a, xq1b, 448, 1, 1, 0);  // t=12
    PH(As1, Bs1, As0, Bs2, xq1a, xq1b, xq0a, xq0b, 480, 1, 1, 0);  // t=13
    PH(As2, Bs2, As1, Bs0, xq0a, xq0b, xq1a, xq1b, 512, 1, 1, 0);  // t=14
    PH(As0, Bs0, As2, Bs1, xq1a, xq1b, xq0a, xq0b, 544, 1, 1, 0);  // t=15
    PH(As1, Bs1, As0, Bs2, xq0a, xq0b, xq1a, xq1b, 576, 1, 1, 0);  // t=16
    PH(As2, Bs2, As1, Bs0, xq1a, xq1b, xq0a, xq0b, 608, 1, 1, 0);  // t=17
    PH(As0, Bs0, As2, Bs1, xq0a, xq0b, xq1a, xq1b, 640, 1, 1, 0);  // t=18
    PH(As1, Bs1, As0, Bs2, xq1a, xq1b, xq0a, xq0b, 672, 1, 1, 0);  // t=19
    PH(As2, Bs2, As1, Bs0, xq0a, xq0b, xq1a, xq1b, 704, 1, 1, 0);  // t=20
    PH(As0, Bs0, As2, Bs1, xq1a, xq1b, xq0a, xq0b, 736, 1, 1, 0);  // t=21
    PH(As1, Bs1, As0, Bs2, xq0a, xq0b, xq1a, xq1b,   0, 0, 1, 0);  // t=22
    PH(As2, Bs2, As0, Bs0, xq0a, xq0b, xq1a, xq1b,   0, 0, 0, 1);  // t=23

#undef STAGE_A
#undef PH
#undef WAIT0
#undef LGKM0
#undef BAR
#undef SCHED0

    // epilogue: D layout col = lane&15, row = (lane>>4)*4 + reg; f16 store
    _Float16* Pb = Ph + (size_t)b * CT * N + bn;
    #pragma unroll
    for (int mi = 0; mi < 8; ++mi)
        #pragma unroll
        for (int ni = 0; ni < 4; ++ni)
            #pragma unroll
            for (int r = 0; r < 4; ++r) {
                const int row = wr * 128 + mi * 16 + sl * 4 + r;
                const int col = wcn * 64 + ni * 16 + fr;
                Pb[(size_t)row * N + col] = (_Float16)acc[mi][ni][r];
            }
}

// ---------------------------------------------------------------------------
// K2 (fused): blocks 0..447 -> BN stats; blocks 448..959 -> softmax stats;
//   softmax blocks with idx<8 also zero lamC.
// ---------------------------------------------------------------------------
__global__ __launch_bounds__(256) void k_stats(
    const _Float16* __restrict__ Ph,
    const float* __restrict__ gq, const float* __restrict__ bq,
    const float* __restrict__ gv, const float* __restrict__ bv,
    float* __restrict__ sArr, float* __restrict__ tArr,
    float* __restrict__ mxk, float* __restrict__ invk,
    float* __restrict__ lamC)
{
    const int bid = blockIdx.x;
    const int tid = threadIdx.x;

    if (bid < CQ + CV) {
        const int ci = bid;
        const int c  = (ci < CQ) ? ci : ci + CK;
        float g, be;
        if (ci < CQ) { g = gq[ci];      be = bq[ci]; }
        else         { g = gv[ci - CQ]; be = bv[ci - CQ]; }

        float s = 0.f, s2 = 0.f;
        for (int b = 0; b < B; ++b) {
            const _Float16* row = Ph + ((size_t)b * CT + c) * N;
            #pragma unroll
            for (int i = 0; i < 2; ++i) {
                f16x8 v = ((const f16x8*)row)[i * 256 + tid];
                #pragma unroll
                for (int j = 0; j < 8; ++j) {
                    float f = (float)v[j];
                    s += f; s2 += f * f;
                }
            }
        }
        #pragma unroll
        for (int off = 32; off; off >>= 1) {
            s  += __shfl_xor(s, off);
            s2 += __shfl_xor(s2, off);
        }
        __shared__ float ls[4], ls2[4];
        if ((tid & 63) == 0) { ls[tid >> 6] = s; ls2[tid >> 6] = s2; }
        __syncthreads();
        if (tid == 0) {
            float S = ls[0] + ls[1] + ls[2] + ls[3];
            float S2 = ls2[0] + ls2[1] + ls2[2] + ls2[3];
            const float invM = 1.0f / (float)(B * N);
            float mean = S * invM;
            float var  = S2 * invM - mean * mean;
            float sc   = g / sqrtf(var + EPS);
            sArr[c] = sc;
            tArr[c] = be - mean * sc;
        }
    } else {
        const int idx = bid - (CQ + CV);        // 0..511
        if (idx < 8) {
            ((float4*)lamC)[idx * 256 + tid] = float4{0.f, 0.f, 0.f, 0.f};
        }
        const int b = idx >> 6, kc = idx & 63;
        const _Float16* row = Ph + ((size_t)b * CT + CQ + kc) * N;
        float v[16];
        float m = -3.4e38f;
        #pragma unroll
        for (int i = 0; i < 2; ++i) {
            f16x8 t = ((const f16x8*)row)[i * 256 + tid];
            #pragma unroll
            for (int j = 0; j < 8; ++j) {
                v[i*8+j] = (float)t[j];
                m = fmaxf(m, v[i*8+j]);
            }
        }
        #pragma unroll
        for (int off = 32; off; off >>= 1) m = fmaxf(m, __shfl_xor(m, off));
        __shared__ float rA[4], rB[4];
        if ((tid & 63) == 0) rA[tid >> 6] = m;
        __syncthreads();
        m = fmaxf(fmaxf(rA[0], rA[1]), fmaxf(rA[2], rA[3]));
        float s = 0.f;
        #pragma unroll
        for (int i = 0; i < 16; ++i) s += __expf(v[i] - m);
        #pragma unroll
        for (int off = 32; off; off >>= 1) s += __shfl_xor(s, off);
        if ((tid & 63) == 0) rB[tid >> 6] = s;
        __syncthreads();
        if (tid == 0) {
            s = rB[0] + rB[1] + rB[2] + rB[3];
            mxk[b * CK + kc]  = m;
            invk[b * CK + kc] = 1.f / s;
        }
    }
}

// ---------------------------------------------------------------------------
// K3: lam_c only. 512 blocks: cx 0..15 (256-n chunks) x u x b -> 2/CU.
// ---------------------------------------------------------------------------
__global__ __launch_bounds__(256) void k_mid(
    const _Float16* __restrict__ Ph, const float* __restrict__ mxk,
    const float* __restrict__ invk, const float* __restrict__ sArr,
    const float* __restrict__ tArr, float* __restrict__ lamC)
{
    __shared__ float Kt[128][20];   // [n][k]
    __shared__ float Vt[128][67];   // [n][v]
    const int bid = blockIdx.x;
    const int tid = threadIdx.x;
    const int cx = bid & 15, u = (bid >> 4) & 3, b = bid >> 6;
    const int chunk0 = cx * 256;
    const int vv = tid & 63, kg = tid >> 6;
    float acc[4] = {0.f, 0.f, 0.f, 0.f};

    const int kk = tid >> 4, sK = tid & 15;
    const float mm = mxk[b * CK + kk * U + u];
    const float iv = invk[b * CK + kk * U + u];

    for (int sc = 0; sc < 2; ++sc) {
        const int nbase = chunk0 + sc * 128;
        __syncthreads();
        {   // Kt: 16 rows x 128 n, one f16x8 per thread
            f16x8 v = *(const f16x8*)(Ph + ((size_t)b * CT + CQ + kk * U + u) * N
                                      + nbase + sK * 8);
            #pragma unroll
            for (int i = 0; i < 8; ++i)
                Kt[sK * 8 + i][kk] = __expf((float)v[i] - mm) * iv;
        }
        {   // Vt: 64 rows x 128 n, four f16x8 per thread
            #pragma unroll
            for (int it = 0; it < 4; ++it) {
                const int task = it * 256 + tid;
                const int vvv = task >> 4, sV = task & 15;
                const int c = CV0 + vvv * U + u;
                f16x8 v = *(const f16x8*)(Ph + ((size_t)b * CT + c) * N
                                          + nbase + sV * 8);
                const float sc2 = sArr[c], tt = tArr[c];
                #pragma unroll
                for (int i = 0; i < 8; ++i)
                    Vt[sV * 8 + i][vvv] = (float)v[i] * sc2 + tt;
            }
        }
        __syncthreads();
        #pragma unroll 4
        for (int n = 0; n < 128; ++n) {
            float4 kv = *(const float4*)&Kt[n][kg * 4];
            float vx = Vt[n][vv];
            acc[0] += kv.x * vx; acc[1] += kv.y * vx;
            acc[2] += kv.z * vx; acc[3] += kv.w * vx;
        }
    }
    #pragma unroll
    for (int j = 0; j < 4; ++j)
        atomicAdd(&lamC[((size_t)b * K + kg * 4 + j) * V + vv], acc[j]);
}

// ---------------------------------------------------------------------------
// K6: fused conv + output. q staged directly from Ph (BN fused).
//   LDS: vsegT 36 KB + qtile 12.25 KB = 48.5 KB -> 3 blocks/CU.
// ---------------------------------------------------------------------------
__global__ __launch_bounds__(512) void k_out(
    const _Float16* __restrict__ Ph, const _Float16* __restrict__ relSg,
    const float* __restrict__ lamC, const float* __restrict__ sArr,
    const float* __restrict__ tArr, float* __restrict__ Y)
{
    constexpr int NT = 32;
    constexpr int VST = 72;                  // np stride (f16), mult of 8
    constexpr int QST = 196;                 // qtile ch-stride (f16)
    __shared__ _Float16 vsegT[256 * VST];    // [u*64+v][np]  (np 0..55 used)
    __shared__ _Float16 qtile[NT * QST];     // [nn][ch]  (ch 0..191 used)

    const int b  = blockIdx.y;
    const int n0 = blockIdx.x * NT;
    const int tid  = threadIdx.x;
    const int lane = tid & 63;
    const int wave = tid >> 6;
    const int fr = lane & 15;   // k row / v col / h row
    const int sl = lane >> 4;   // slot 0..3

    // --- stage vsegT: 256 ch x 8 aligned f16x8 segs = 2048 tasks, 4/thread
    #pragma unroll
    for (int it = 0; it < 4; ++it) {
        const int task = it * 512 + tid;
        const int ch = task >> 3, s = task & 7;
        const int c = CV0 + ch;
        const int row = (ch & 3) * 64 + (ch >> 2);
        const int nbase = n0 - 16 + s * 8;          // 16B-aligned (n0 % 32 == 0)
        const float sc = sArr[c], tt = tArr[c];
        const bool full = (nbase >= 0) && (nbase + 8 <= N);
        f16x8 v{};
        if (full)
            v = *(const f16x8*)(Ph + ((size_t)b * CT + c) * N + nbase);
        #pragma unroll
        for (int i = 0; i < 8; ++i) {
            const int np = s * 8 - 5 + i;           // nbase-(n0-PAD)+i
            if (np < 0 || np >= 56) continue;
            float val = 0.f;
            if (full) {
                val = (float)v[i] * sc + tt;
            } else {
                const int n = nbase + i;
                if (n >= 0 && n < N)
                    val = (float)Ph[((size_t)b * CT + c) * N + n] * sc + tt;
            }
            vsegT[row * VST + np] = (_Float16)val;
        }
    }
    // --- stage qtile (BN fused, transposed): 192 ch x 4 segs = 768 tasks
    for (int task = tid; task < CQ * 4; task += 512) {
        const int ch = task >> 2, s = task & 3;
        f16x8 v = *(const f16x8*)(Ph + ((size_t)b * CT + ch) * N + n0 + s * 8);
        const float sc = sArr[ch], tt = tArr[ch];
        #pragma unroll
        for (int i = 0; i < 8; ++i)
            qtile[(s * 8 + i) * QST + ch] = (_Float16)((float)v[i] * sc + tt);
    }
    // --- lamC fragment (C-layout): row k = sl*4+r, col v = vg*16+fr
    const int vg = wave & 3;
    const int nb = (wave >> 2) * 16;
    float lc[4];
    #pragma unroll
    for (int r = 0; r < 4; ++r)
        lc[r] = lamC[(size_t)b * K * V + (sl * 4 + r) * V + vg * 16 + fr];
    __syncthreads();

    for (int dlt = 0; dlt < 8; ++dlt) {
        f16x8 aU[4];
        #pragma unroll
        for (int u = 0; u < 4; ++u)
            aU[u] = *(const f16x8*)(relSg + ((dlt * 4 + u) * 16 + fr) * 32 + sl * 8);
        #pragma unroll
        for (int rep = 0; rep < 2; ++rep) {
            const int A  = nb + rep * 8;
            const int nn = A + dlt;
            f32x4 acc = {lc[0], lc[1], lc[2], lc[3]};
            #pragma unroll
            for (int u = 0; u < 4; ++u) {
                f16x8 bf = *(const f16x8*)(vsegT + (u * 64 + vg * 16 + fr) * VST + A + sl * 8);
                acc = __builtin_amdgcn_mfma_f32_16x16x32_f16(aU[u], bf, acc, 0, 0, 0);
            }
            f16x4 lam16;
            #pragma unroll
            for (int r = 0; r < 4; ++r) lam16[r] = (_Float16)acc[r];
            f16x4 q4 = *(const f16x4*)(qtile + nn * QST + fr * 16 + sl * 4);
            f32x4 y = {0.f, 0.f, 0.f, 0.f};
            y = __builtin_amdgcn_mfma_f32_16x16x16f16(q4, lam16, y, 0, 0, 0);
            if (sl < 3) {
                float* yr = Y + ((size_t)b * N + n0 + nn) * (H * V) + vg * 16 + fr;
                #pragma unroll
                for (int r = 0; r < 4; ++r)
                    yr[(sl * 4 + r) * 64] = y[r];
            }
        }
    }
}

// ---------------------------------------------------------------------------
extern "C" void kernel_launch(void* const* d_in, const int* in_sizes, int n_in,
                              void* d_out, int out_size, void* d_ws, size_t ws_size,
                              hipStream_t stream)
{
    const float* x   = (const float*)d_in[0];
    const float* Wq  = (const float*)d_in[1];
    const float* Wk  = (const float*)d_in[2];
    const float* Wv  = (const float*)d_in[3];
    const float* gq  = (const float*)d_in[4];
    const float* bq  = (const float*)d_in[5];
    const float* gv  = (const float*)d_in[6];
    const float* bv  = (const float*)d_in[7];
    const float* rel = (const float*)d_in[8];
    float* Y = (float*)d_out;

    _Float16* Ph  = (_Float16*)d_ws;                  // B*CT*N f16 (32 MiB)
    float* sArr = (float*)(Ph + (size_t)B * CT * N);  // CT
    float* tArr = sArr + CT;                          // CT
    float* lamC = tArr + CT;                          // B*K*V = 8192
    float* mxk  = lamC + (size_t)B * K * V;           // B*CK
    float* invk = mxk + B * CK;                       // B*CK
    _Float16* Wh = (_Float16*)(invk + B * CK);        // CT*D f16 (786 KB)
    _Float16* relSg = Wh + (size_t)CT * D;            // 16384 f16 (32 KB)

    k_w16  <<<dim3(192 + 8), 256, 0, stream>>>(Wq, Wk, Wv, rel, Wh, relSg);
    k_proj <<<dim3(N / 128, 1, B), 512, 0, stream>>>(x, Wh, Ph);
    k_stats<<<dim3(CQ + CV + B * CK), 256, 0, stream>>>(Ph, gq, bq, gv, bv,
                                                        sArr, tArr, mxk, invk, lamC);
    k_mid  <<<dim3(512), 256, 0, stream>>>(Ph, mxk, invk, sArr, tArr, lamC);
    k_out  <<<dim3(N / 32, B), 512, 0, stream>>>(Ph, relSg, lamC, sArr, tArr, Y);
}

// Round 21
// 106.914 us; speedup vs baseline: 1.0580x; 1.0580x over previous
//
#include <hip/hip_runtime.h>
#include <hip/hip_bf16.h>

// Problem constants
constexpr int B = 8, N = 4096, D = 768;
constexpr int H = 12, K = 16, U = 4, V = 64, L = 23, PAD = 11;
constexpr int CQ = 192;           // q channels [0,192)
constexpr int CK = 64;            // k channels [192,256)
constexpr int CV = 256;           // v channels [256,512)
constexpr int CT = 512;           // total channels
constexpr int CV0 = CQ + CK;      // 256
constexpr float EPS = 1e-5f;

typedef _Float16 f16x8 __attribute__((ext_vector_type(8)));
typedef _Float16 f16x4 __attribute__((ext_vector_type(4)));
typedef _Float16 f16x2 __attribute__((ext_vector_type(2)));
typedef float    f32x4 __attribute__((ext_vector_type(4)));

#define GLOAD16(gp, lp) __builtin_amdgcn_global_load_lds( \
    (const __attribute__((address_space(1))) void*)(gp),  \
    (__attribute__((address_space(3))) void*)(lp), 16, 0, 0)

__device__ __forceinline__ f16x2 pkrtz(float a, float b) {
    return __builtin_bit_cast(f16x2, __builtin_amdgcn_cvt_pkrtz(a, b));
}

__device__ __forceinline__ f16x8 cvt8r(float4 a, float4 b) {
    f16x8 r;
    r[0] = (_Float16)a.x; r[1] = (_Float16)a.y; r[2] = (_Float16)a.z; r[3] = (_Float16)a.w;
    r[4] = (_Float16)b.x; r[5] = (_Float16)b.y; r[6] = (_Float16)b.z; r[7] = (_Float16)b.w;
    return r;
}

// ---------------------------------------------------------------------------
// K0: bid<192: pack Wq|Wk|Wv -> Wh[512][768] f16.
//     bid>=192 (8 blocks): precompute shifted rel table to GLOBAL:
//     relSg[d][u][k][j] = f16(rel[k][u][j-d]), 0 outside.
// ---------------------------------------------------------------------------
__global__ __launch_bounds__(256) void k_w16(
    const float* __restrict__ Wq, const float* __restrict__ Wk,
    const float* __restrict__ Wv, const float* __restrict__ rel,
    _Float16* __restrict__ Wh, _Float16* __restrict__ relSg)
{
    const int bid = blockIdx.x;
    const int tid = threadIdx.x;
    if (bid < 192) {
        const int idx = bid * 256 + tid;   // 49152 groups of 8
        const int c = idx / 96, g = idx % 96;
        const float* src;
        if (c < CQ)       src = Wq + (size_t)c * D;
        else if (c < CV0) src = Wk + (size_t)(c - CQ) * D;
        else              src = Wv + (size_t)(c - CV0) * D;
        float4 a = *(const float4*)(src + g * 8);
        float4 b = *(const float4*)(src + g * 8 + 4);
        *(f16x8*)(Wh + (size_t)c * D + g * 8) = cvt8r(a, b);
    } else {
        // 8 blocks x 256 thr x 8 elems = 16384 = 8*4*16*32
        const int base = ((bid - 192) * 256 + tid) * 8;
        f16x8 o;
        #pragma unroll
        for (int j = 0; j < 8; ++j) {
            const int e = base + j;
            const int jj = e & 31, kk = (e >> 5) & 15;
            const int uu = (e >> 9) & 3, dd = e >> 11;
            const int l = jj - dd;
            float v = (l >= 0 && l < L) ? rel[(kk * U + uu) * L + l] : 0.f;
            o[j] = (_Float16)v;
        }
        *(f16x8*)(relSg + base) = o;
    }
}

// ---------------------------------------------------------------------------
// K1: projection GEMM — 512c x 128n tile, 8 waves, ring-3 LDS, counted
//   vmcnt(6), early-ds-read + setprio phase. (R16/R17/R19 verified, 57 us)
//   NOTE: structure floor — R14 (tile shrink), R18 (LDS squeeze for 2/CU),
//   R20 (f16-B + WAIT0) all regressed. Do not modify without a full
//   8-phase co-designed port.
// ---------------------------------------------------------------------------
__global__ __launch_bounds__(512) void k_proj(
    const float* __restrict__ x, const _Float16* __restrict__ Wh,
    _Float16* __restrict__ Ph)
{
    __shared__ _Float16 As0[512 * 32], As1[512 * 32], As2[512 * 32];
    __shared__ float    Bs0[128 * 32], Bs1[128 * 32], Bs2[128 * 32];
    const int b  = blockIdx.z;
    const int bn = blockIdx.x * 128;
    const int tid  = threadIdx.x;
    const int lane = tid & 63;
    const int wave = tid >> 6;        // 0..7
    const int wr  = wave >> 1;        // c quarter 0..3 (128c each)
    const int wcn = wave & 1;         // n half 0..1 (64n each)
    const int fr = lane & 15, sl = lane >> 4;

    const int arow_l = lane >> 2;     // 0..15
    const int achk   = (lane & 3) ^ (arow_l & 3) ^ ((arow_l >> 2) & 3);
    const int brow_l = lane >> 3;     // 0..7
    const int bchk   = (lane & 7) ^ brow_l;

    const _Float16* Wbase = Wh;                        // full 512 channels
    const float*    xbase = x + ((size_t)b * N + bn) * D;

    const int ca = sl ^ (fr & 3) ^ ((fr >> 2) & 3);     // A chunk 0..3
    const int mb = fr & 7;                              // B row mask

    f32x4 acc[8][4] = {};

#define STAGE(Ap, Bp, kt) do {                                         \
        _Pragma("unroll")                                              \
        for (int j = 0; j < 4; ++j) {                                  \
            const int r0 = wave * 64 + j * 16;                         \
            GLOAD16(Wbase + (size_t)(r0 + arow_l) * D + (kt) + achk * 8, \
                    (Ap) + r0 * 32);                                   \
        }                                                              \
        _Pragma("unroll")                                              \
        for (int j = 0; j < 2; ++j) {                                  \
            const int r0 = wave * 16 + j * 8;                          \
            GLOAD16(xbase + (size_t)(r0 + brow_l) * D + (kt) + bchk * 4, \
                    (Bp) + r0 * 32);                                   \
        }                                                              \
    } while (0)

#define WAIT6  asm volatile("s_waitcnt vmcnt(6)" ::: "memory")
#define WAIT0  asm volatile("s_waitcnt vmcnt(0)" ::: "memory")
#define BAR    __builtin_amdgcn_s_barrier()
#define SCHED0 __builtin_amdgcn_sched_barrier(0)

#define PHASE(Ap, Bp, StageStmt, WaitStmt) do {                        \
        f16x8 af[8]; float4 pa[4], pb[4];                              \
        _Pragma("unroll")                                              \
        for (int mi = 0; mi < 8; ++mi) {                               \
            const int ra = wr * 128 + mi * 16 + fr;                    \
            af[mi] = *(const f16x8*)((Ap) + ra * 32 + ca * 8);         \
        }                                                              \
        _Pragma("unroll")                                              \
        for (int ni = 0; ni < 4; ++ni) {                               \
            const int rb = wcn * 64 + ni * 16 + fr;                    \
            pa[ni] = *(const float4*)((Bp) + rb * 32 + (((sl * 2) ^ mb) * 4)); \
            pb[ni] = *(const float4*)((Bp) + rb * 32 + (((sl * 2 + 1) ^ mb) * 4)); \
        }                                                              \
        StageStmt;                                                     \
        WaitStmt;                                                      \
        SCHED0; BAR;                                                   \
        f16x8 bfr[4];                                                  \
        _Pragma("unroll")                                              \
        for (int ni = 0; ni < 4; ++ni) {                               \
            f16x2 p0 = pkrtz(pa[ni].x, pa[ni].y);                      \
            f16x2 p1 = pkrtz(pa[ni].z, pa[ni].w);                      \
            f16x2 p2 = pkrtz(pb[ni].x, pb[ni].y);                      \
            f16x2 p3 = pkrtz(pb[ni].z, pb[ni].w);                      \
            f16x8 bv;                                                  \
            bv[0] = p0[0]; bv[1] = p0[1]; bv[2] = p1[0]; bv[3] = p1[1]; \
            bv[4] = p2[0]; bv[5] = p2[1]; bv[6] = p3[0]; bv[7] = p3[1]; \
            bfr[ni] = bv;                                              \
        }                                                              \
        __builtin_amdgcn_s_setprio(1);                                 \
        _Pragma("unroll")                                              \
        for (int mi = 0; mi < 8; ++mi)                                 \
            _Pragma("unroll")                                          \
            for (int ni = 0; ni < 4; ++ni)                             \
                acc[mi][ni] = __builtin_amdgcn_mfma_f32_16x16x32_f16(  \
                    af[mi], bfr[ni], acc[mi][ni], 0, 0, 0);            \
        __builtin_amdgcn_s_setprio(0);                                 \
        SCHED0; BAR;                                                   \
    } while (0)

    STAGE(As0, Bs0, 0);
    STAGE(As1, Bs1, 32);
    WAIT6;
    BAR;

    for (int t0 = 0; t0 < 21; t0 += 3) {
        const int kt = t0 * 32;
        PHASE(As0, Bs0, STAGE(As2, Bs2, kt + 64),  WAIT6);
        PHASE(As1, Bs1, STAGE(As0, Bs0, kt + 96),  WAIT6);
        PHASE(As2, Bs2, STAGE(As1, Bs1, kt + 128), WAIT6);
    }
    PHASE(As0, Bs0, STAGE(As2, Bs2, 736), WAIT6);
    PHASE(As1, Bs1, (void)0, WAIT0);
    PHASE(As2, Bs2, (void)0, (void)0);

#undef STAGE
#undef PHASE
#undef WAIT6
#undef WAIT0
#undef BAR
#undef SCHED0

    // epilogue: D layout col = lane&15, row = (lane>>4)*4 + reg; f16 store
    _Float16* Pb = Ph + (size_t)b * CT * N + bn;
    #pragma unroll
    for (int mi = 0; mi < 8; ++mi)
        #pragma unroll
        for (int ni = 0; ni < 4; ++ni)
            #pragma unroll
            for (int r = 0; r < 4; ++r) {
                const int row = wr * 128 + mi * 16 + sl * 4 + r;
                const int col = wcn * 64 + ni * 16 + fr;
                Pb[(size_t)row * N + col] = (_Float16)acc[mi][ni][r];
            }
}

// ---------------------------------------------------------------------------
// K2 (fused): blocks 0..447 -> BN stats; blocks 448..959 -> softmax stats;
//   softmax blocks with idx<8 also zero lamC.
// ---------------------------------------------------------------------------
__global__ __launch_bounds__(256) void k_stats(
    const _Float16* __restrict__ Ph,
    const float* __restrict__ gq, const float* __restrict__ bq,
    const float* __restrict__ gv, const float* __restrict__ bv,
    float* __restrict__ sArr, float* __restrict__ tArr,
    float* __restrict__ mxk, float* __restrict__ invk,
    float* __restrict__ lamC)
{
    const int bid = blockIdx.x;
    const int tid = threadIdx.x;

    if (bid < CQ + CV) {
        const int ci = bid;
        const int c  = (ci < CQ) ? ci : ci + CK;
        float g, be;
        if (ci < CQ) { g = gq[ci];      be = bq[ci]; }
        else         { g = gv[ci - CQ]; be = bv[ci - CQ]; }

        float s = 0.f, s2 = 0.f;
        for (int b = 0; b < B; ++b) {
            const _Float16* row = Ph + ((size_t)b * CT + c) * N;
            #pragma unroll
            for (int i = 0; i < 2; ++i) {
                f16x8 v = ((const f16x8*)row)[i * 256 + tid];
                #pragma unroll
                for (int j = 0; j < 8; ++j) {
                    float f = (float)v[j];
                    s += f; s2 += f * f;
                }
            }
        }
        #pragma unroll
        for (int off = 32; off; off >>= 1) {
            s  += __shfl_xor(s, off);
            s2 += __shfl_xor(s2, off);
        }
        __shared__ float ls[4], ls2[4];
        if ((tid & 63) == 0) { ls[tid >> 6] = s; ls2[tid >> 6] = s2; }
        __syncthreads();
        if (tid == 0) {
            float S = ls[0] + ls[1] + ls[2] + ls[3];
            float S2 = ls2[0] + ls2[1] + ls2[2] + ls2[3];
            const float invM = 1.0f / (float)(B * N);
            float mean = S * invM;
            float var  = S2 * invM - mean * mean;
            float sc   = g / sqrtf(var + EPS);
            sArr[c] = sc;
            tArr[c] = be - mean * sc;
        }
    } else {
        const int idx = bid - (CQ + CV);        // 0..511
        if (idx < 8) {
            ((float4*)lamC)[idx * 256 + tid] = float4{0.f, 0.f, 0.f, 0.f};
        }
        const int b = idx >> 6, kc = idx & 63;
        const _Float16* row = Ph + ((size_t)b * CT + CQ + kc) * N;
        float v[16];
        float m = -3.4e38f;
        #pragma unroll
        for (int i = 0; i < 2; ++i) {
            f16x8 t = ((const f16x8*)row)[i * 256 + tid];
            #pragma unroll
            for (int j = 0; j < 8; ++j) {
                v[i*8+j] = (float)t[j];
                m = fmaxf(m, v[i*8+j]);
            }
        }
        #pragma unroll
        for (int off = 32; off; off >>= 1) m = fmaxf(m, __shfl_xor(m, off));
        __shared__ float rA[4], rB[4];
        if ((tid & 63) == 0) rA[tid >> 6] = m;
        __syncthreads();
        m = fmaxf(fmaxf(rA[0], rA[1]), fmaxf(rA[2], rA[3]));
        float s = 0.f;
        #pragma unroll
        for (int i = 0; i < 16; ++i) s += __expf(v[i] - m);
        #pragma unroll
        for (int off = 32; off; off >>= 1) s += __shfl_xor(s, off);
        if ((tid & 63) == 0) rB[tid >> 6] = s;
        __syncthreads();
        if (tid == 0) {
            s = rB[0] + rB[1] + rB[2] + rB[3];
            mxk[b * CK + kc]  = m;
            invk[b * CK + kc] = 1.f / s;
        }
    }
}

// ---------------------------------------------------------------------------
// K3: lam_c only. 512 blocks: cx 0..15 (256-n chunks) x u x b -> 2/CU.
// ---------------------------------------------------------------------------
__global__ __launch_bounds__(256) void k_mid(
    const _Float16* __restrict__ Ph, const float* __restrict__ mxk,
    const float* __restrict__ invk, const float* __restrict__ sArr,
    const float* __restrict__ tArr, float* __restrict__ lamC)
{
    __shared__ float Kt[128][20];   // [n][k]
    __shared__ float Vt[128][67];   // [n][v]
    const int bid = blockIdx.x;
    const int tid = threadIdx.x;
    const int cx = bid & 15, u = (bid >> 4) & 3, b = bid >> 6;
    const int chunk0 = cx * 256;
    const int vv = tid & 63, kg = tid >> 6;
    float acc[4] = {0.f, 0.f, 0.f, 0.f};

    const int kk = tid >> 4, sK = tid & 15;
    const float mm = mxk[b * CK + kk * U + u];
    const float iv = invk[b * CK + kk * U + u];

    for (int sc = 0; sc < 2; ++sc) {
        const int nbase = chunk0 + sc * 128;
        __syncthreads();
        {   // Kt: 16 rows x 128 n, one f16x8 per thread
            f16x8 v = *(const f16x8*)(Ph + ((size_t)b * CT + CQ + kk * U + u) * N
                                      + nbase + sK * 8);
            #pragma unroll
            for (int i = 0; i < 8; ++i)
                Kt[sK * 8 + i][kk] = __expf((float)v[i] - mm) * iv;
        }
        {   // Vt: 64 rows x 128 n, four f16x8 per thread
            #pragma unroll
            for (int it = 0; it < 4; ++it) {
                const int task = it * 256 + tid;
                const int vvv = task >> 4, sV = task & 15;
                const int c = CV0 + vvv * U + u;
                f16x8 v = *(const f16x8*)(Ph + ((size_t)b * CT + c) * N
                                          + nbase + sV * 8);
                const float sc2 = sArr[c], tt = tArr[c];
                #pragma unroll
                for (int i = 0; i < 8; ++i)
                    Vt[sV * 8 + i][vvv] = (float)v[i] * sc2 + tt;
            }
        }
        __syncthreads();
        #pragma unroll 4
        for (int n = 0; n < 128; ++n) {
            float4 kv = *(const float4*)&Kt[n][kg * 4];
            float vx = Vt[n][vv];
            acc[0] += kv.x * vx; acc[1] += kv.y * vx;
            acc[2] += kv.z * vx; acc[3] += kv.w * vx;
        }
    }
    #pragma unroll
    for (int j = 0; j < 4; ++j)
        atomicAdd(&lamC[((size_t)b * K + kg * 4 + j) * V + vv], acc[j]);
}

// ---------------------------------------------------------------------------
// K6: fused conv + output. q staged directly from Ph (BN fused).
//   LDS: vsegT 36 KB + qtile 12.25 KB = 48.5 KB -> 3 blocks/CU.
// ---------------------------------------------------------------------------
__global__ __launch_bounds__(512) void k_out(
    const _Float16* __restrict__ Ph, const _Float16* __restrict__ relSg,
    const float* __restrict__ lamC, const float* __restrict__ sArr,
    const float* __restrict__ tArr, float* __restrict__ Y)
{
    constexpr int NT = 32;
    constexpr int VST = 72;                  // np stride (f16), mult of 8
    constexpr int QST = 196;                 // qtile ch-stride (f16)
    __shared__ _Float16 vsegT[256 * VST];    // [u*64+v][np]  (np 0..55 used)
    __shared__ _Float16 qtile[NT * QST];     // [nn][ch]  (ch 0..191 used)

    const int b  = blockIdx.y;
    const int n0 = blockIdx.x * NT;
    const int tid  = threadIdx.x;
    const int lane = tid & 63;
    const int wave = tid >> 6;
    const int fr = lane & 15;   // k row / v col / h row
    const int sl = lane >> 4;   // slot 0..3

    // --- stage vsegT: 256 ch x 8 aligned f16x8 segs = 2048 tasks, 4/thread
    #pragma unroll
    for (int it = 0; it < 4; ++it) {
        const int task = it * 512 + tid;
        const int ch = task >> 3, s = task & 7;
        const int c = CV0 + ch;
        const int row = (ch & 3) * 64 + (ch >> 2);
        const int nbase = n0 - 16 + s * 8;          // 16B-aligned (n0 % 32 == 0)
        const float sc = sArr[c], tt = tArr[c];
        const bool full = (nbase >= 0) && (nbase + 8 <= N);
        f16x8 v{};
        if (full)
            v = *(const f16x8*)(Ph + ((size_t)b * CT + c) * N + nbase);
        #pragma unroll
        for (int i = 0; i < 8; ++i) {
            const int np = s * 8 - 5 + i;           // nbase-(n0-PAD)+i
            if (np < 0 || np >= 56) continue;
            float val = 0.f;
            if (full) {
                val = (float)v[i] * sc + tt;
            } else {
                const int n = nbase + i;
                if (n >= 0 && n < N)
                    val = (float)Ph[((size_t)b * CT + c) * N + n] * sc + tt;
            }
            vsegT[row * VST + np] = (_Float16)val;
        }
    }
    // --- stage qtile (BN fused, transposed): 192 ch x 4 segs = 768 tasks
    for (int task = tid; task < CQ * 4; task += 512) {
        const int ch = task >> 2, s = task & 3;
        f16x8 v = *(const f16x8*)(Ph + ((size_t)b * CT + ch) * N + n0 + s * 8);
        const float sc = sArr[ch], tt = tArr[ch];
        #pragma unroll
        for (int i = 0; i < 8; ++i)
            qtile[(s * 8 + i) * QST + ch] = (_Float16)((float)v[i] * sc + tt);
    }
    // --- lamC fragment (C-layout): row k = sl*4+r, col v = vg*16+fr
    const int vg = wave & 3;
    const int nb = (wave >> 2) * 16;
    float lc[4];
    #pragma unroll
    for (int r = 0; r < 4; ++r)
        lc[r] = lamC[(size_t)b * K * V + (sl * 4 + r) * V + vg * 16 + fr];
    __syncthreads();

    for (int dlt = 0; dlt < 8; ++dlt) {
        f16x8 aU[4];
        #pragma unroll
        for (int u = 0; u < 4; ++u)
            aU[u] = *(const f16x8*)(relSg + ((dlt * 4 + u) * 16 + fr) * 32 + sl * 8);
        #pragma unroll
        for (int rep = 0; rep < 2; ++rep) {
            const int A  = nb + rep * 8;
            const int nn = A + dlt;
            f32x4 acc = {lc[0], lc[1], lc[2], lc[3]};
            #pragma unroll
            for (int u = 0; u < 4; ++u) {
                f16x8 bf = *(const f16x8*)(vsegT + (u * 64 + vg * 16 + fr) * VST + A + sl * 8);
                acc = __builtin_amdgcn_mfma_f32_16x16x32_f16(aU[u], bf, acc, 0, 0, 0);
            }
            f16x4 lam16;
            #pragma unroll
            for (int r = 0; r < 4; ++r) lam16[r] = (_Float16)acc[r];
            f16x4 q4 = *(const f16x4*)(qtile + nn * QST + fr * 16 + sl * 4);
            f32x4 y = {0.f, 0.f, 0.f, 0.f};
            y = __builtin_amdgcn_mfma_f32_16x16x16f16(q4, lam16, y, 0, 0, 0);
            if (sl < 3) {
                float* yr = Y + ((size_t)b * N + n0 + nn) * (H * V) + vg * 16 + fr;
                #pragma unroll
                for (int r = 0; r < 4; ++r)
                    yr[(sl * 4 + r) * 64] = y[r];
            }
        }
    }
}

// ---------------------------------------------------------------------------
extern "C" void kernel_launch(void* const* d_in, const int* in_sizes, int n_in,
                              void* d_out, int out_size, void* d_ws, size_t ws_size,
                              hipStream_t stream)
{
    const float* x   = (const float*)d_in[0];
    const float* Wq  = (const float*)d_in[1];
    const float* Wk  = (const float*)d_in[2];
    const float* Wv  = (const float*)d_in[3];
    const float* gq  = (const float*)d_in[4];
    const float* bq  = (const float*)d_in[5];
    const float* gv  = (const float*)d_in[6];
    const float* bv  = (const float*)d_in[7];
    const float* rel = (const float*)d_in[8];
    float* Y = (float*)d_out;

    _Float16* Ph  = (_Float16*)d_ws;                  // B*CT*N f16 (32 MiB)
    float* sArr = (float*)(Ph + (size_t)B * CT * N);  // CT
    float* tArr = sArr + CT;                          // CT
    float* lamC = tArr + CT;                          // B*K*V = 8192
    float* mxk  = lamC + (size_t)B * K * V;           // B*CK
    float* invk = mxk + B * CK;                       // B*CK
    _Float16* Wh = (_Float16*)(invk + B * CK);        // CT*D f16 (786 KB)
    _Float16* relSg = Wh + (size_t)CT * D;            // 16384 f16 (32 KB)

    k_w16  <<<dim3(192 + 8), 256, 0, stream>>>(Wq, Wk, Wv, rel, Wh, relSg);
    k_proj <<<dim3(N / 128, 1, B), 512, 0, stream>>>(x, Wh, Ph);
    k_stats<<<dim3(CQ + CV + B * CK), 256, 0, stream>>>(Ph, gq, bq, gv, bv,
                                                        sArr, tArr, mxk, invk, lamC);
    k_mid  <<<dim3(512), 256, 0, stream>>>(Ph, mxk, invk, sArr, tArr, lamC);
    k_out  <<<dim3(N / 32, B), 512, 0, stream>>>(Ph, relSg, lamC, sArr, tArr, Y);
}